// Round 1
// baseline (5791.120 us; speedup 1.0000x reference)
//
#include <hip/hip_runtime.h>

// ---------------------------------------------------------------------------
// Decision-transformer forward on MI355X (gfx950).
// bf16 MFMA GEMMs + fp32 residual stream + flash attention.
// ---------------------------------------------------------------------------

typedef __bf16 bf16_t;
typedef __bf16 bf16x8 __attribute__((ext_vector_type(8)));
typedef float  f32x4  __attribute__((ext_vector_type(4)));

#define MFMA16(a, b, c) __builtin_amdgcn_mfma_f32_16x16x32_bf16((a), (b), (c), 0, 0, 0)

// Problem constants (fixed-size problem).
// B=4, T=1024, S=128, C=1024, H=16, NL=8, VOCAB=4096, L=2048, Dh=64.

// ---------------------------------------------------------------------------
// Weight transpose + f32->bf16 convert:  src[K][N] f32  ->  dst[N][K] bf16
// grid: (N/64, K/64, layers); block 256
// ---------------------------------------------------------------------------
__global__ __launch_bounds__(256)
void transpose_cvt(const float* __restrict__ src, bf16_t* __restrict__ dst,
                   int K, int N, long src_ls, long dst_ls)
{
    __shared__ float tl[64][65];
    const int tid = threadIdx.x;
    src += (long)blockIdx.z * src_ls;
    dst += (long)blockIdx.z * dst_ls;
    const int n0 = blockIdx.x * 64, k0 = blockIdx.y * 64;
#pragma unroll
    for (int i = 0; i < 16; ++i) {
        const int idx = tid + 256 * i;
        tl[idx >> 6][idx & 63] = src[(long)(k0 + (idx >> 6)) * N + n0 + (idx & 63)];
    }
    __syncthreads();
#pragma unroll
    for (int i = 0; i < 16; ++i) {
        const int idx = tid + 256 * i;
        dst[(long)(n0 + (idx >> 6)) * K + k0 + (idx & 63)] = (bf16_t)tl[idx & 63][idx >> 6];
    }
}

// ---------------------------------------------------------------------------
// Concatenate bq/bk/bv -> bqkv [NL][3072]
// ---------------------------------------------------------------------------
__global__ __launch_bounds__(256)
void concat_bias(const float* __restrict__ bq, const float* __restrict__ bk,
                 const float* __restrict__ bv, float* __restrict__ dst)
{
    const int i = blockIdx.x * 256 + threadIdx.x;   // 8*3072 = 24576 exact
    const int l = i / 3072, c = i % 3072;
    float v;
    if (c < 1024)      v = bq[l * 1024 + c];
    else if (c < 2048) v = bk[l * 1024 + c - 1024];
    else               v = bv[l * 1024 + c - 2048];
    dst[i] = v;
}

// ---------------------------------------------------------------------------
// Embedding: x[b][2t][c]   = tanh(states@W_se+b_se) + gpe + pos_emb[2t]
//            x[b][2t+1][c] = tanh(act_table[a])     + gpe + pos_emb[2t+1]
// grid: (T/4, B); block 256; 4 tokens per block (W_se L2 reuse)
// ---------------------------------------------------------------------------
__global__ __launch_bounds__(256)
void embed_kernel(const float* __restrict__ states, const int* __restrict__ pre_act,
                  const int* __restrict__ tsteps, const float* __restrict__ W_se,
                  const float* __restrict__ b_se, const float* __restrict__ act_tab,
                  const float* __restrict__ pos_emb, const float* __restrict__ gpos,
                  float* __restrict__ x)
{
    __shared__ float st[4][128];
    const int tid = threadIdx.x;
    const int bb = blockIdx.y;
    const int t0 = blockIdx.x * 4;
#pragma unroll
    for (int i = 0; i < 2; ++i) {
        const int ii = tid + 256 * i;
        st[ii >> 7][ii & 127] = states[((long)bb * 1024 + t0 + (ii >> 7)) * 128 + (ii & 127)];
    }
    __syncthreads();
    int ts[4], ac[4];
#pragma unroll
    for (int tk = 0; tk < 4; ++tk) {
        ts[tk] = tsteps[bb * 1024 + t0 + tk];
        ac[tk] = pre_act[bb * 1024 + t0 + tk];
    }
    for (int ci = 0; ci < 4; ++ci) {
        const int c = ci * 256 + tid;
        float acc[4];
        const float bs = b_se[c];
#pragma unroll
        for (int tk = 0; tk < 4; ++tk) acc[tk] = bs;
        for (int s = 0; s < 128; ++s) {
            const float w = W_se[s * 1024 + c];
#pragma unroll
            for (int tk = 0; tk < 4; ++tk) acc[tk] = fmaf(st[tk][s], w, acc[tk]);
        }
#pragma unroll
        for (int tk = 0; tk < 4; ++tk) {
            const int t = t0 + tk;
            const float g = gpos[(long)ts[tk] * 1024 + c];
            const float se = tanhf(acc[tk]) + g + pos_emb[(long)(2 * t) * 1024 + c];
            const float ae = tanhf(act_tab[(long)ac[tk] * 1024 + c]) + g
                             + pos_emb[(long)(2 * t + 1) * 1024 + c];
            x[((long)bb * 2048 + 2 * t) * 1024 + c]     = se;
            x[((long)bb * 2048 + 2 * t + 1) * 1024 + c] = ae;
        }
    }
}

// ---------------------------------------------------------------------------
// LayerNorm over C=1024, fp32 in -> bf16 out.
// odd=1: input row = b*2048 + 2t + 1, output row = b*1024 + t (head compaction)
// grid: rows; block 256 (each thread 4 consecutive elems)
// ---------------------------------------------------------------------------
__global__ __launch_bounds__(256)
void ln_kernel(const float* __restrict__ x, const float* __restrict__ g,
               const float* __restrict__ be, bf16_t* __restrict__ out, int odd)
{
    const int row = blockIdx.x;
    const long rin = odd ? ((long)(row >> 10) * 2048 + (long)(row & 1023) * 2 + 1) : (long)row;
    const int tid = threadIdx.x;
    const float4 v = ((const float4*)(x + rin * 1024))[tid];
    float s = v.x + v.y + v.z + v.w;
    float q = v.x * v.x + v.y * v.y + v.z * v.z + v.w * v.w;
#pragma unroll
    for (int off = 1; off < 64; off <<= 1) {
        s += __shfl_xor(s, off);
        q += __shfl_xor(q, off);
    }
    __shared__ float red[8];
    if ((tid & 63) == 0) { red[(tid >> 6) * 2] = s; red[(tid >> 6) * 2 + 1] = q; }
    __syncthreads();
    s = red[0] + red[2] + red[4] + red[6];
    q = red[1] + red[3] + red[5] + red[7];
    const float mean = s * (1.f / 1024.f);
    const float var  = q * (1.f / 1024.f) - mean * mean;
    const float rstd = rsqrtf(var + 1e-5f);
    const float4 gg = ((const float4*)g)[tid];
    const float4 bb = ((const float4*)be)[tid];
    union { bf16_t e[4]; uint2 u; } o;
    o.e[0] = (bf16_t)((v.x - mean) * rstd * gg.x + bb.x);
    o.e[1] = (bf16_t)((v.y - mean) * rstd * gg.y + bb.y);
    o.e[2] = (bf16_t)((v.z - mean) * rstd * gg.z + bb.z);
    o.e[3] = (bf16_t)((v.w - mean) * rstd * gg.w + bb.w);
    ((uint2*)(out + (long)row * 1024))[tid] = o.u;
}

// ---------------------------------------------------------------------------
// GEMM: D[M,N] = epilogue(A[M,K] @ Bt[N,K]^T + bias)
// A, Bt bf16; 128x128x32 tile; 4 waves, each 64x64 via 4x4 MFMA 16x16x32.
// mode 0: bf16 out  | 1: gelu->bf16 | 2: fp32 += (residual) | 3: fp32 out
// grid: (N/128, M/128); block 256
// ---------------------------------------------------------------------------
__global__ __launch_bounds__(256)
void gemm_bt(const bf16_t* __restrict__ A, const bf16_t* __restrict__ Bt,
             const float* __restrict__ bias, void* __restrict__ D,
             int M, int N, int K, int ldd, int mode)
{
    __shared__ bf16_t As[128 * 40] __attribute__((aligned(16)));
    __shared__ bf16_t Bs[128 * 40] __attribute__((aligned(16)));
    const int tid = threadIdx.x;
    const int m0 = blockIdx.y * 128, n0 = blockIdx.x * 128;
    const int wave = tid >> 6, lane = tid & 63, ln = lane & 15, quad = lane >> 4;
    const int wm = (wave & 1) * 64, wn = (wave >> 1) * 64;

    f32x4 acc[4][4];
#pragma unroll
    for (int i = 0; i < 4; ++i)
#pragma unroll
        for (int j = 0; j < 4; ++j) acc[i][j] = (f32x4){0.f, 0.f, 0.f, 0.f};

    const int am = tid >> 2, kc = (tid & 3) * 8;   // chunk mapping
    const bf16_t* Ag0 = A + (long)(m0 + am) * K + kc;
    const bf16_t* Ag1 = A + (long)(m0 + 64 + am) * K + kc;
    const bf16_t* Bg0 = Bt + (long)(n0 + am) * K + kc;
    const bf16_t* Bg1 = Bt + (long)(n0 + 64 + am) * K + kc;
    const int w0 = am * 40 + kc, w1 = (64 + am) * 40 + kc;

    const int nkt = K >> 5;
    for (int kt = 0; kt < nkt; ++kt) {
        const int ko = kt * 32;
        const uint4 ra0 = *(const uint4*)(Ag0 + ko);
        const uint4 ra1 = *(const uint4*)(Ag1 + ko);
        const uint4 rb0 = *(const uint4*)(Bg0 + ko);
        const uint4 rb1 = *(const uint4*)(Bg1 + ko);
        __syncthreads();
        *(uint4*)&As[w0] = ra0;
        *(uint4*)&As[w1] = ra1;
        *(uint4*)&Bs[w0] = rb0;
        *(uint4*)&Bs[w1] = rb1;
        __syncthreads();
        bf16x8 af[4], bfb[4];
#pragma unroll
        for (int i = 0; i < 4; ++i) af[i]  = *(const bf16x8*)&As[(wm + i * 16 + ln) * 40 + quad * 8];
#pragma unroll
        for (int j = 0; j < 4; ++j) bfb[j] = *(const bf16x8*)&Bs[(wn + j * 16 + ln) * 40 + quad * 8];
#pragma unroll
        for (int i = 0; i < 4; ++i)
#pragma unroll
            for (int j = 0; j < 4; ++j)
                acc[i][j] = MFMA16(af[i], bfb[j], acc[i][j]);
    }

#pragma unroll
    for (int j = 0; j < 4; ++j) {
        const int col = n0 + wn + j * 16 + ln;
        const float bv = bias ? bias[col] : 0.f;
#pragma unroll
        for (int i = 0; i < 4; ++i) {
            const int row0 = m0 + wm + i * 16 + quad * 4;
#pragma unroll
            for (int r = 0; r < 4; ++r) {
                const float v = acc[i][j][r] + bv;
                const long idx = (long)(row0 + r) * ldd + col;
                if (mode == 0) {
                    ((bf16_t*)D)[idx] = (bf16_t)v;
                } else if (mode == 1) {
                    const float gl = 0.5f * v * (1.f + erff(v * 0.70710678118654752f));
                    ((bf16_t*)D)[idx] = (bf16_t)gl;
                } else if (mode == 2) {
                    ((float*)D)[idx] += v;
                } else {
                    ((float*)D)[idx] = v;
                }
            }
        }
    }
}

// ---------------------------------------------------------------------------
// Flash attention, causal. qkv bf16 [B*L][3072] (q|k|v, each col h*64+d).
// grid: (L/64, B*H); block 256 (4 waves; wave w owns q rows qb+w*16..+15).
// 32-key tiles; MFMA 16x16x32 for QK^T and PV; online softmax.
// ---------------------------------------------------------------------------
__global__ __launch_bounds__(256)
void flash_attn(const bf16_t* __restrict__ qkv, bf16_t* __restrict__ y)
{
    __shared__ bf16_t Kl[32 * 72]     __attribute__((aligned(16)));  // K rows, pad 72
    __shared__ bf16_t Vt[64 * 36]     __attribute__((aligned(16)));  // V^T [dh][kpos], pad 36
    __shared__ bf16_t Pl[4][16 * 40]  __attribute__((aligned(16)));  // per-wave P, pad 40

    const int tid = threadIdx.x;
    const int wave = tid >> 6, lane = tid & 63, ln = lane & 15, quad = lane >> 4;
    const int b = blockIdx.y >> 4, h = blockIdx.y & 15;
    const int qb = blockIdx.x * 64;
    const long rowbase = (long)b * 2048;

    const int qrow = qb + wave * 16 + ln;
    const bf16_t* qp = qkv + (rowbase + qrow) * 3072 + h * 64;
    const bf16x8 qa0 = *(const bf16x8*)(qp + quad * 8);
    const bf16x8 qa1 = *(const bf16x8*)(qp + 32 + quad * 8);

    f32x4 O[4];
#pragma unroll
    for (int g = 0; g < 4; ++g) O[g] = (f32x4){0.f, 0.f, 0.f, 0.f};
    float m_run[4] = {-1e30f, -1e30f, -1e30f, -1e30f};
    float l_run[4] = {0.f, 0.f, 0.f, 0.f};

    const int srow = tid >> 3;          // 0..31 key row
    const int sch  = (tid & 7) * 8;     // dh chunk start
    const int nkt = blockIdx.x * 2 + 2;

    for (int kt = 0; kt < nkt; ++kt) {
        const int kb = kt * 32;
        const bf16_t* kp = qkv + (rowbase + kb + srow) * 3072 + 1024 + h * 64 + sch;
        const bf16_t* vp = qkv + (rowbase + kb + srow) * 3072 + 2048 + h * 64 + sch;
        const uint4 kq = *(const uint4*)kp;
        union { uint4 q; bf16_t e[8]; } vv;
        vv.q = *(const uint4*)vp;
        __syncthreads();                 // prior tile's LDS reads done
        *(uint4*)&Kl[srow * 72 + sch] = kq;
#pragma unroll
        for (int j = 0; j < 8; ++j) Vt[(sch + j) * 36 + srow] = vv.e[j];
        __syncthreads();                 // staging visible

        // ---- scores: S[16q x 32k] as two 16x16 C-frags ----
        f32x4 S0 = (f32x4){0.f, 0.f, 0.f, 0.f};
        f32x4 S1 = (f32x4){0.f, 0.f, 0.f, 0.f};
        const bf16x8 k0lo = *(const bf16x8*)&Kl[ln * 72 + quad * 8];
        const bf16x8 k0hi = *(const bf16x8*)&Kl[ln * 72 + 32 + quad * 8];
        const bf16x8 k1lo = *(const bf16x8*)&Kl[(16 + ln) * 72 + quad * 8];
        const bf16x8 k1hi = *(const bf16x8*)&Kl[(16 + ln) * 72 + 32 + quad * 8];
        S0 = MFMA16(qa0, k0lo, S0); S0 = MFMA16(qa1, k0hi, S0);
        S1 = MFMA16(qa0, k1lo, S1); S1 = MFMA16(qa1, k1hi, S1);

        // ---- online softmax (rows quad*4+r; 16-lane row groups) ----
        float alpha[4];
#pragma unroll
        for (int r = 0; r < 4; ++r) {
            const int qg = qb + wave * 16 + quad * 4 + r;
            const float s0 = (kb + ln <= qg)      ? S0[r] * 0.125f : -1e30f;
            const float s1 = (kb + 16 + ln <= qg) ? S1[r] * 0.125f : -1e30f;
            float mx = fmaxf(s0, s1);
            mx = fmaxf(mx, __shfl_xor(mx, 1));
            mx = fmaxf(mx, __shfl_xor(mx, 2));
            mx = fmaxf(mx, __shfl_xor(mx, 4));
            mx = fmaxf(mx, __shfl_xor(mx, 8));
            const float mn = fmaxf(m_run[r], mx);
            alpha[r] = __expf(m_run[r] - mn);
            m_run[r] = mn;
            const float p0 = __expf(s0 - mn);
            const float p1 = __expf(s1 - mn);
            float rs = p0 + p1;
            rs += __shfl_xor(rs, 1);
            rs += __shfl_xor(rs, 2);
            rs += __shfl_xor(rs, 4);
            rs += __shfl_xor(rs, 8);
            l_run[r] = l_run[r] * alpha[r] + rs;
            Pl[wave][(quad * 4 + r) * 40 + ln]      = (bf16_t)p0;
            Pl[wave][(quad * 4 + r) * 40 + 16 + ln] = (bf16_t)p1;
        }
        __syncthreads();                 // order P writes before A-frag reads

        // ---- rescale O, then O += P @ V ----
#pragma unroll
        for (int g = 0; g < 4; ++g)
#pragma unroll
            for (int r = 0; r < 4; ++r) O[g][r] *= alpha[r];

        const bf16x8 pa = *(const bf16x8*)&Pl[wave][ln * 40 + quad * 8];
#pragma unroll
        for (int g = 0; g < 4; ++g) {
            union { uint2 u[2]; bf16x8 v; } vb;
            const bf16_t* vtp = &Vt[(g * 16 + ln) * 36 + quad * 8];
            vb.u[0] = *(const uint2*)vtp;
            vb.u[1] = *(const uint2*)(vtp + 4);
            O[g] = MFMA16(pa, vb.v, O[g]);
        }
    }

#pragma unroll
    for (int r = 0; r < 4; ++r) {
        const float inv = 1.f / l_run[r];
        const long orow = rowbase + qb + wave * 16 + quad * 4 + r;
#pragma unroll
        for (int g = 0; g < 4; ++g)
            y[orow * 1024 + h * 64 + g * 16 + ln] = (bf16_t)(O[g][r] * inv);
    }
}

// ---------------------------------------------------------------------------
// Host orchestration
// ---------------------------------------------------------------------------
extern "C" void kernel_launch(void* const* d_in, const int* in_sizes, int n_in,
                              void* d_out, int out_size, void* d_ws, size_t ws_size,
                              hipStream_t stream)
{
    (void)in_sizes; (void)n_in; (void)out_size; (void)ws_size;

    const float* states  = (const float*)d_in[0];
    const int*   pre_act = (const int*)d_in[1];
    const int*   tsteps  = (const int*)d_in[2];
    const float* W_se    = (const float*)d_in[3];
    const float* b_se    = (const float*)d_in[4];
    const float* act_tab = (const float*)d_in[5];
    const float* pos_emb = (const float*)d_in[6];
    const float* gpos    = (const float*)d_in[7];
    const float* ln1_g   = (const float*)d_in[8];
    const float* ln1_b   = (const float*)d_in[9];
    const float* Wq      = (const float*)d_in[10];
    const float* bq      = (const float*)d_in[11];
    const float* Wk      = (const float*)d_in[12];
    const float* bk      = (const float*)d_in[13];
    const float* Wv      = (const float*)d_in[14];
    const float* bv      = (const float*)d_in[15];
    const float* Wo      = (const float*)d_in[16];
    const float* bo      = (const float*)d_in[17];
    const float* ln2_g   = (const float*)d_in[18];
    const float* ln2_b   = (const float*)d_in[19];
    const float* W1      = (const float*)d_in[20];
    const float* b1      = (const float*)d_in[21];
    const float* W2      = (const float*)d_in[22];
    const float* b2      = (const float*)d_in[23];
    const float* lnf_g   = (const float*)d_in[24];
    const float* lnf_b   = (const float*)d_in[25];
    const float* W_head  = (const float*)d_in[26];

    char* w = (char*)d_ws;
    float*  x      = (float*)(w + 0);              // 32 MB  [8192][1024] f32
    bf16_t* h      = (bf16_t*)(w + 33554432);      // 16 MB  [8192][1024]
    bf16_t* qkv    = (bf16_t*)(w + 50331648);      // 48 MB  [8192][3072]
    bf16_t* y      = (bf16_t*)(w + 100663296);     // 16 MB  [8192][1024]
    bf16_t* m1     = (bf16_t*)(w + 117440512);     // 32 MB  [8192][2048]
    bf16_t* hf     = (bf16_t*)(w + 150994944);     //  8 MB  [4096][1024]
    bf16_t* Wqkv_t = (bf16_t*)(w + 159383552);     // 48 MB  [NL][3072][1024]
    bf16_t* Wo_t   = (bf16_t*)(w + 209715200);     // 16 MB  [NL][1024][1024]
    bf16_t* W1_t   = (bf16_t*)(w + 226492416);     // 32 MB  [NL][2048][1024]
    bf16_t* W2_t   = (bf16_t*)(w + 260046848);     // 32 MB  [NL][1024][2048]
    bf16_t* Wh_t   = (bf16_t*)(w + 293601280);     //  8 MB  [4096][1024]
    float*  bqkv   = (float*)(w + 301989888);      // 96 KB  [NL][3072]

    const dim3 blk(256);

    // weight conversion / transposition (B^T layout for gemm_bt)
    transpose_cvt<<<dim3(16, 16, 8), blk, 0, stream>>>(Wq, Wqkv_t,                 1024, 1024, 1048576, 3145728);
    transpose_cvt<<<dim3(16, 16, 8), blk, 0, stream>>>(Wk, Wqkv_t + 1048576,       1024, 1024, 1048576, 3145728);
    transpose_cvt<<<dim3(16, 16, 8), blk, 0, stream>>>(Wv, Wqkv_t + 2097152,       1024, 1024, 1048576, 3145728);
    transpose_cvt<<<dim3(16, 16, 8), blk, 0, stream>>>(Wo, Wo_t,                   1024, 1024, 1048576, 1048576);
    transpose_cvt<<<dim3(32, 16, 8), blk, 0, stream>>>(W1, W1_t,                   1024, 2048, 2097152, 2097152);
    transpose_cvt<<<dim3(16, 32, 8), blk, 0, stream>>>(W2, W2_t,                   2048, 1024, 2097152, 2097152);
    transpose_cvt<<<dim3(64, 16, 1), blk, 0, stream>>>(W_head, Wh_t,               1024, 4096, 0, 0);
    concat_bias<<<96, blk, 0, stream>>>(bq, bk, bv, bqkv);

    embed_kernel<<<dim3(256, 4), blk, 0, stream>>>(states, pre_act, tsteps, W_se, b_se,
                                                   act_tab, pos_emb, gpos, x);

    for (int l = 0; l < 8; ++l) {
        ln_kernel<<<8192, blk, 0, stream>>>(x, ln1_g + l * 1024, ln1_b + l * 1024, h, 0);
        gemm_bt<<<dim3(24, 64), blk, 0, stream>>>(h, Wqkv_t + (long)l * 3145728, bqkv + l * 3072,
                                                  qkv, 8192, 3072, 1024, 3072, 0);
        flash_attn<<<dim3(32, 64), blk, 0, stream>>>(qkv, y);
        gemm_bt<<<dim3(8, 64), blk, 0, stream>>>(y, Wo_t + (long)l * 1048576, bo + l * 1024,
                                                 x, 8192, 1024, 1024, 1024, 2);
        ln_kernel<<<8192, blk, 0, stream>>>(x, ln2_g + l * 1024, ln2_b + l * 1024, h, 0);
        gemm_bt<<<dim3(16, 64), blk, 0, stream>>>(h, W1_t + (long)l * 2097152, b1 + l * 2048,
                                                  m1, 8192, 2048, 1024, 2048, 1);
        gemm_bt<<<dim3(8, 64), blk, 0, stream>>>(m1, W2_t + (long)l * 2097152, b2 + l * 1024,
                                                 x, 8192, 1024, 2048, 1024, 2);
    }

    ln_kernel<<<4096, blk, 0, stream>>>(x, lnf_g, lnf_b, hf, 1);
    gemm_bt<<<dim3(32, 32), blk, 0, stream>>>(hf, Wh_t, nullptr, d_out,
                                              4096, 4096, 1024, 4096, 3);
}

// Round 2
// 3684.451 us; speedup vs baseline: 1.5718x; 1.5718x over previous
//
#include <hip/hip_runtime.h>

// ---------------------------------------------------------------------------
// Decision-transformer forward on MI355X (gfx950).
// bf16 MFMA GEMMs (m97-style global_load_lds staging) + fp32 residual stream
// + flash attention (O^T form, ones-row l-sum, no max-subtraction).
// ---------------------------------------------------------------------------

typedef __bf16 bf16_t;
typedef __bf16 bf16x8 __attribute__((ext_vector_type(8)));
typedef float  f32x4  __attribute__((ext_vector_type(4)));

#define MFMA16(a, b, c) __builtin_amdgcn_mfma_f32_16x16x32_bf16((a), (b), (c), 0, 0, 0)

__device__ __forceinline__ void gload_lds16(const void* g, void* l) {
    __builtin_amdgcn_global_load_lds(
        (const __attribute__((address_space(1))) unsigned int*)g,
        (__attribute__((address_space(3))) unsigned int*)l, 16, 0, 0);
}

// Problem constants: B=4, T=1024, S=128, C=1024, H=16, NL=8, VOCAB=4096, L=2048.

// ---------------------------------------------------------------------------
// Weight transpose + f32->bf16 convert (+scale): src[K][N] f32 -> dst[N][K] bf16
// ---------------------------------------------------------------------------
__global__ __launch_bounds__(256)
void transpose_cvt(const float* __restrict__ src, bf16_t* __restrict__ dst,
                   int K, int N, long src_ls, long dst_ls, float scale)
{
    __shared__ float tl[64][65];
    const int tid = threadIdx.x;
    src += (long)blockIdx.z * src_ls;
    dst += (long)blockIdx.z * dst_ls;
    const int n0 = blockIdx.x * 64, k0 = blockIdx.y * 64;
#pragma unroll
    for (int i = 0; i < 16; ++i) {
        const int idx = tid + 256 * i;
        tl[idx >> 6][idx & 63] = src[(long)(k0 + (idx >> 6)) * N + n0 + (idx & 63)];
    }
    __syncthreads();
#pragma unroll
    for (int i = 0; i < 16; ++i) {
        const int idx = tid + 256 * i;
        dst[(long)(n0 + (idx >> 6)) * K + k0 + (idx & 63)] = (bf16_t)(tl[idx & 63][idx >> 6] * scale);
    }
}

// ---------------------------------------------------------------------------
// Concatenate bq*0.125 / bk / bv -> bqkv [NL][3072]
// ---------------------------------------------------------------------------
__global__ __launch_bounds__(256)
void concat_bias(const float* __restrict__ bq, const float* __restrict__ bk,
                 const float* __restrict__ bv, float* __restrict__ dst)
{
    const int i = blockIdx.x * 256 + threadIdx.x;   // 8*3072 = 24576 exact
    const int l = i / 3072, c = i % 3072;
    float v;
    if (c < 1024)      v = bq[l * 1024 + c] * 0.125f;
    else if (c < 2048) v = bk[l * 1024 + c - 1024];
    else               v = bv[l * 1024 + c - 2048];
    dst[i] = v;
}

// ---------------------------------------------------------------------------
// Embedding
// ---------------------------------------------------------------------------
__global__ __launch_bounds__(256)
void embed_kernel(const float* __restrict__ states, const int* __restrict__ pre_act,
                  const int* __restrict__ tsteps, const float* __restrict__ W_se,
                  const float* __restrict__ b_se, const float* __restrict__ act_tab,
                  const float* __restrict__ pos_emb, const float* __restrict__ gpos,
                  float* __restrict__ x)
{
    __shared__ float st[4][128];
    const int tid = threadIdx.x;
    const int bb = blockIdx.y;
    const int t0 = blockIdx.x * 4;
#pragma unroll
    for (int i = 0; i < 2; ++i) {
        const int ii = tid + 256 * i;
        st[ii >> 7][ii & 127] = states[((long)bb * 1024 + t0 + (ii >> 7)) * 128 + (ii & 127)];
    }
    __syncthreads();
    int ts[4], ac[4];
#pragma unroll
    for (int tk = 0; tk < 4; ++tk) {
        ts[tk] = tsteps[bb * 1024 + t0 + tk];
        ac[tk] = pre_act[bb * 1024 + t0 + tk];
    }
    for (int ci = 0; ci < 4; ++ci) {
        const int c = ci * 256 + tid;
        float acc[4];
        const float bs = b_se[c];
#pragma unroll
        for (int tk = 0; tk < 4; ++tk) acc[tk] = bs;
        for (int s = 0; s < 128; ++s) {
            const float w = W_se[s * 1024 + c];
#pragma unroll
            for (int tk = 0; tk < 4; ++tk) acc[tk] = fmaf(st[tk][s], w, acc[tk]);
        }
#pragma unroll
        for (int tk = 0; tk < 4; ++tk) {
            const int t = t0 + tk;
            const float g = gpos[(long)ts[tk] * 1024 + c];
            const float se = tanhf(acc[tk]) + g + pos_emb[(long)(2 * t) * 1024 + c];
            const float ae = tanhf(act_tab[(long)ac[tk] * 1024 + c]) + g
                             + pos_emb[(long)(2 * t + 1) * 1024 + c];
            x[((long)bb * 2048 + 2 * t) * 1024 + c]     = se;
            x[((long)bb * 2048 + 2 * t + 1) * 1024 + c] = ae;
        }
    }
}

// ---------------------------------------------------------------------------
// LayerNorm over C=1024, fp32 in -> bf16 out. odd=1: compact odd rows for head.
// ---------------------------------------------------------------------------
__global__ __launch_bounds__(256)
void ln_kernel(const float* __restrict__ x, const float* __restrict__ g,
               const float* __restrict__ be, bf16_t* __restrict__ out, int odd)
{
    const int row = blockIdx.x;
    const long rin = odd ? ((long)(row >> 10) * 2048 + (long)(row & 1023) * 2 + 1) : (long)row;
    const int tid = threadIdx.x;
    const float4 v = ((const float4*)(x + rin * 1024))[tid];
    float s = v.x + v.y + v.z + v.w;
    float q = v.x * v.x + v.y * v.y + v.z * v.z + v.w * v.w;
#pragma unroll
    for (int off = 1; off < 64; off <<= 1) {
        s += __shfl_xor(s, off);
        q += __shfl_xor(q, off);
    }
    __shared__ float red[8];
    if ((tid & 63) == 0) { red[(tid >> 6) * 2] = s; red[(tid >> 6) * 2 + 1] = q; }
    __syncthreads();
    s = red[0] + red[2] + red[4] + red[6];
    q = red[1] + red[3] + red[5] + red[7];
    const float mean = s * (1.f / 1024.f);
    const float var  = q * (1.f / 1024.f) - mean * mean;
    const float rstd = rsqrtf(var + 1e-5f);
    const float4 gg = ((const float4*)g)[tid];
    const float4 bb = ((const float4*)be)[tid];
    union { bf16_t e[4]; uint2 u; } o;
    o.e[0] = (bf16_t)((v.x - mean) * rstd * gg.x + bb.x);
    o.e[1] = (bf16_t)((v.y - mean) * rstd * gg.y + bb.y);
    o.e[2] = (bf16_t)((v.z - mean) * rstd * gg.z + bb.z);
    o.e[3] = (bf16_t)((v.w - mean) * rstd * gg.w + bb.w);
    ((uint2*)(out + (long)row * 1024))[tid] = o.u;
}

// ---------------------------------------------------------------------------
// GEMM: D[M,N] = epilogue(A[M,K] @ Bt[N,K]^T + bias)   (m97 structure)
// 128x128x32 tile; global_load_lds width-16 staging into unpadded LDS slabs.
// mode 0: bf16 out | 1: gelu->bf16 | 2: fp32 += | 3: fp32 out
// ---------------------------------------------------------------------------
__global__ __launch_bounds__(256)
void gemm_bt(const bf16_t* __restrict__ A, const bf16_t* __restrict__ Bt,
             const float* __restrict__ bias, void* __restrict__ D,
             int M, int N, int K, int ldd, int mode)
{
    __shared__ bf16_t As[128 * 32] __attribute__((aligned(16)));
    __shared__ bf16_t Bs[128 * 32] __attribute__((aligned(16)));
    const int tid = threadIdx.x;
    const int m0 = blockIdx.y * 128, n0 = blockIdx.x * 128;
    const int wave = tid >> 6, lane = tid & 63, ln = lane & 15, quad = lane >> 4;
    const int wm = (wave & 1) * 64, wn = (wave >> 1) * 64;

    f32x4 acc[4][4];
#pragma unroll
    for (int i = 0; i < 4; ++i)
#pragma unroll
        for (int j = 0; j < 4; ++j) acc[i][j] = (f32x4){0.f, 0.f, 0.f, 0.f};

    // staging: wave w slab rows [w*16, w*16+16); lane l -> row l>>2, chunk (l&3)*8
    const int srow = wave * 16 + (lane >> 2);
    const int scol = (lane & 3) * 8;
    const bf16_t* Ag0 = A  + (long)(m0 + srow) * K + scol;
    const bf16_t* Ag1 = A  + (long)(m0 + 64 + srow) * K + scol;
    const bf16_t* Bg0 = Bt + (long)(n0 + srow) * K + scol;
    const bf16_t* Bg1 = Bt + (long)(n0 + 64 + srow) * K + scol;
    bf16_t* Al0 = &As[(wave * 16) * 32];
    bf16_t* Al1 = &As[(64 + wave * 16) * 32];
    bf16_t* Bl0 = &Bs[(wave * 16) * 32];
    bf16_t* Bl1 = &Bs[(64 + wave * 16) * 32];

    const int nkt = K >> 5;
    for (int kt = 0; kt < nkt; ++kt) {
        const int ko = kt * 32;
        __syncthreads();                      // prior tile's ds_reads drained
        gload_lds16(Ag0 + ko, Al0);
        gload_lds16(Ag1 + ko, Al1);
        gload_lds16(Bg0 + ko, Bl0);
        gload_lds16(Bg1 + ko, Bl1);
        __syncthreads();                      // vmcnt(0) drain -> staged
        bf16x8 af[4], bfb[4];
#pragma unroll
        for (int i = 0; i < 4; ++i) af[i]  = *(const bf16x8*)&As[(wm + i * 16 + ln) * 32 + quad * 8];
#pragma unroll
        for (int j = 0; j < 4; ++j) bfb[j] = *(const bf16x8*)&Bs[(wn + j * 16 + ln) * 32 + quad * 8];
#pragma unroll
        for (int i = 0; i < 4; ++i)
#pragma unroll
            for (int j = 0; j < 4; ++j)
                acc[i][j] = MFMA16(af[i], bfb[j], acc[i][j]);
    }

#pragma unroll
    for (int j = 0; j < 4; ++j) {
        const int col = n0 + wn + j * 16 + ln;
        const float bv = bias ? bias[col] : 0.f;
#pragma unroll
        for (int i = 0; i < 4; ++i) {
            const int row0 = m0 + wm + i * 16 + quad * 4;
#pragma unroll
            for (int r = 0; r < 4; ++r) {
                const float v = acc[i][j][r] + bv;
                const long idx = (long)(row0 + r) * ldd + col;
                if (mode == 0) {
                    ((bf16_t*)D)[idx] = (bf16_t)v;
                } else if (mode == 1) {
                    const float gl = 0.5f * v * (1.f + erff(v * 0.70710678118654752f));
                    ((bf16_t*)D)[idx] = (bf16_t)gl;
                } else if (mode == 2) {
                    ((float*)D)[idx] += v;
                } else {
                    ((float*)D)[idx] = v;
                }
            }
        }
    }
}

// ---------------------------------------------------------------------------
// Flash attention, causal. qkv bf16 [B*L][3072] (q|k|v; q pre-scaled by 1/8).
// grid (16, B*H); block 256. Block handles q-tile pair (x, 31-x): uniform 33
// key-tiles of 64. Computes O^T = V^T @ P^T; l via ones-row of V^T; no
// max-subtraction (scores bounded, fp32-safe).
// ---------------------------------------------------------------------------
__global__ __launch_bounds__(256)
void flash_attn(const bf16_t* __restrict__ qkv, bf16_t* __restrict__ y)
{
    __shared__ bf16_t Kl[64 * 72]      __attribute__((aligned(16)));  // [key][dh]
    __shared__ bf16_t Vt[80 * 72]      __attribute__((aligned(16)));  // [dh|ones|junk][key]
    __shared__ bf16_t Pl[4][16 * 72]   __attribute__((aligned(16)));  // per-wave P [q][key]

    const int tid = threadIdx.x;
    const int wave = tid >> 6, lane = tid & 63, ln = lane & 15, quad = lane >> 4;
    const int b = blockIdx.y >> 4, h = blockIdx.y & 15;
    const long rowbase = (long)b * 2048;

    // ones row (d=64) + zero junk rows 65..79 (written once, never overwritten)
    for (int i = tid; i < 16 * 72; i += 256)
        Vt[64 * 72 + i] = (i < 72) ? (bf16_t)1.0f : (bf16_t)0.0f;

    const int krow = tid >> 3, kch = (tid & 7) * 8;   // K staging
    const int vd = tid & 63, vq = tid >> 6;           // V transposed staging

    for (int pp = 0; pp < 2; ++pp) {
        const int qt = pp ? (31 - (int)blockIdx.x) : (int)blockIdx.x;
        const int qrow0 = qt * 64 + wave * 16;
        const bf16_t* qp = qkv + (rowbase + qrow0 + ln) * 3072 + h * 64;
        const bf16x8 qa0 = *(const bf16x8*)(qp + quad * 8);
        const bf16x8 qa1 = *(const bf16x8*)(qp + 32 + quad * 8);

        f32x4 Of[5];
#pragma unroll
        for (int g = 0; g < 5; ++g) Of[g] = (f32x4){0.f, 0.f, 0.f, 0.f};

        for (int kt = 0; kt <= qt; ++kt) {
            const int kb = kt * 64;
            // --- fetch to regs (before barrier) ---
            const bf16_t* kpg = qkv + (rowbase + kb) * 3072 + 1024 + h * 64;
            const uint4 k0 = *(const uint4*)(kpg + (long)krow * 3072 + kch);
            const uint4 k1 = *(const uint4*)(kpg + (long)(32 + krow) * 3072 + kch);
            const bf16_t* vpg = qkv + (rowbase + kb + vq * 16) * 3072 + 2048 + h * 64 + vd;
            union { uint4 u[2]; bf16_t e[16]; } vr;
#pragma unroll
            for (int i = 0; i < 16; ++i) vr.e[i] = vpg[(long)i * 3072];
            __syncthreads();                 // prior tile's LDS reads done
            *(uint4*)&Kl[krow * 72 + kch]        = k0;
            *(uint4*)&Kl[(32 + krow) * 72 + kch] = k1;
            *(uint4*)&Vt[vd * 72 + vq * 16]      = vr.u[0];
            *(uint4*)&Vt[vd * 72 + vq * 16 + 8]  = vr.u[1];
            __syncthreads();                 // staged tile visible

            // --- scores S[16q x 64k] (4 col-group frags) ---
            f32x4 S[4];
#pragma unroll
            for (int g = 0; g < 4; ++g) {
                S[g] = (f32x4){0.f, 0.f, 0.f, 0.f};
                S[g] = MFMA16(qa0, *(const bf16x8*)&Kl[(g * 16 + ln) * 72 + quad * 8], S[g]);
                S[g] = MFMA16(qa1, *(const bf16x8*)&Kl[(g * 16 + ln) * 72 + 32 + quad * 8], S[g]);
            }

            // --- exp + P store (wave-private LDS region, no barrier needed) ---
            bf16_t* Pw = &Pl[wave][0];
            if (kt == qt) {
#pragma unroll
                for (int g = 0; g < 4; ++g)
#pragma unroll
                    for (int r = 0; r < 4; ++r) {
                        const int lim = wave * 16 + quad * 4 + r;
                        const float p = (g * 16 + ln <= lim) ? __expf(S[g][r]) : 0.f;
                        Pw[(quad * 4 + r) * 72 + g * 16 + ln] = (bf16_t)p;
                    }
            } else {
#pragma unroll
                for (int g = 0; g < 4; ++g)
#pragma unroll
                    for (int r = 0; r < 4; ++r)
                        Pw[(quad * 4 + r) * 72 + g * 16 + ln] = (bf16_t)__expf(S[g][r]);
            }

            // --- O^T += V^T @ P^T  (g=4 row accumulates l via ones-row) ---
            const bf16x8 p0 = *(const bf16x8*)&Pw[ln * 72 + quad * 8];
            const bf16x8 p1 = *(const bf16x8*)&Pw[ln * 72 + 32 + quad * 8];
#pragma unroll
            for (int g = 0; g < 5; ++g) {
                Of[g] = MFMA16(*(const bf16x8*)&Vt[(g * 16 + ln) * 72 + quad * 8],      p0, Of[g]);
                Of[g] = MFMA16(*(const bf16x8*)&Vt[(g * 16 + ln) * 72 + 32 + quad * 8], p1, Of[g]);
            }
        }

        // --- epilogue: normalize by l (sum lives in lane (quad=0, ln), reg 0) ---
        const float lsum = __shfl(Of[4][0], ln);
        const float inv = 1.f / lsum;
        const long orow = rowbase + qt * 64 + wave * 16 + ln;
#pragma unroll
        for (int g = 0; g < 4; ++g) {
            union { bf16_t e[4]; uint2 u; } o;
#pragma unroll
            for (int r = 0; r < 4; ++r) o.e[r] = (bf16_t)(Of[g][r] * inv);
            *(uint2*)&y[orow * 1024 + h * 64 + g * 16 + quad * 4] = o.u;
        }
    }
}

// ---------------------------------------------------------------------------
// Host orchestration
// ---------------------------------------------------------------------------
extern "C" void kernel_launch(void* const* d_in, const int* in_sizes, int n_in,
                              void* d_out, int out_size, void* d_ws, size_t ws_size,
                              hipStream_t stream)
{
    (void)in_sizes; (void)n_in; (void)out_size; (void)ws_size;

    const float* states  = (const float*)d_in[0];
    const int*   pre_act = (const int*)d_in[1];
    const int*   tsteps  = (const int*)d_in[2];
    const float* W_se    = (const float*)d_in[3];
    const float* b_se    = (const float*)d_in[4];
    const float* act_tab = (const float*)d_in[5];
    const float* pos_emb = (const float*)d_in[6];
    const float* gpos    = (const float*)d_in[7];
    const float* ln1_g   = (const float*)d_in[8];
    const float* ln1_b   = (const float*)d_in[9];
    const float* Wq      = (const float*)d_in[10];
    const float* bq      = (const float*)d_in[11];
    const float* Wk      = (const float*)d_in[12];
    const float* bk      = (const float*)d_in[13];
    const float* Wv      = (const float*)d_in[14];
    const float* bv      = (const float*)d_in[15];
    const float* Wo      = (const float*)d_in[16];
    const float* bo      = (const float*)d_in[17];
    const float* ln2_g   = (const float*)d_in[18];
    const float* ln2_b   = (const float*)d_in[19];
    const float* W1      = (const float*)d_in[20];
    const float* b1      = (const float*)d_in[21];
    const float* W2      = (const float*)d_in[22];
    const float* b2      = (const float*)d_in[23];
    const float* lnf_g   = (const float*)d_in[24];
    const float* lnf_b   = (const float*)d_in[25];
    const float* W_head  = (const float*)d_in[26];

    char* w = (char*)d_ws;
    float*  x      = (float*)(w + 0);              // 32 MB  [8192][1024] f32
    bf16_t* h      = (bf16_t*)(w + 33554432);      // 16 MB  [8192][1024]
    bf16_t* qkv    = (bf16_t*)(w + 50331648);      // 48 MB  [8192][3072]
    bf16_t* y      = (bf16_t*)(w + 100663296);     // 16 MB  [8192][1024]
    bf16_t* m1     = (bf16_t*)(w + 117440512);     // 32 MB  [8192][2048]
    bf16_t* hf     = (bf16_t*)(w + 150994944);     //  8 MB  [4096][1024]
    bf16_t* Wqkv_t = (bf16_t*)(w + 159383552);     // 48 MB  [NL][3072][1024]
    bf16_t* Wo_t   = (bf16_t*)(w + 209715200);     // 16 MB  [NL][1024][1024]
    bf16_t* W1_t   = (bf16_t*)(w + 226492416);     // 32 MB  [NL][2048][1024]
    bf16_t* W2_t   = (bf16_t*)(w + 260046848);     // 32 MB  [NL][1024][2048]
    bf16_t* Wh_t   = (bf16_t*)(w + 293601280);     //  8 MB  [4096][1024]
    float*  bqkv   = (float*)(w + 301989888);      // 96 KB  [NL][3072]

    const dim3 blk(256);

    // weight conversion (B^T layout); Wq/bq pre-scaled by 1/sqrt(Dh)=0.125
    transpose_cvt<<<dim3(16, 16, 8), blk, 0, stream>>>(Wq, Wqkv_t,           1024, 1024, 1048576, 3145728, 0.125f);
    transpose_cvt<<<dim3(16, 16, 8), blk, 0, stream>>>(Wk, Wqkv_t + 1048576, 1024, 1024, 1048576, 3145728, 1.f);
    transpose_cvt<<<dim3(16, 16, 8), blk, 0, stream>>>(Wv, Wqkv_t + 2097152, 1024, 1024, 1048576, 3145728, 1.f);
    transpose_cvt<<<dim3(16, 16, 8), blk, 0, stream>>>(Wo, Wo_t,             1024, 1024, 1048576, 1048576, 1.f);
    transpose_cvt<<<dim3(32, 16, 8), blk, 0, stream>>>(W1, W1_t,             1024, 2048, 2097152, 2097152, 1.f);
    transpose_cvt<<<dim3(16, 32, 8), blk, 0, stream>>>(W2, W2_t,             2048, 1024, 2097152, 2097152, 1.f);
    transpose_cvt<<<dim3(64, 16, 1), blk, 0, stream>>>(W_head, Wh_t,         1024, 4096, 0, 0, 1.f);
    concat_bias<<<96, blk, 0, stream>>>(bq, bk, bv, bqkv);

    embed_kernel<<<dim3(256, 4), blk, 0, stream>>>(states, pre_act, tsteps, W_se, b_se,
                                                   act_tab, pos_emb, gpos, x);

    for (int l = 0; l < 8; ++l) {
        ln_kernel<<<8192, blk, 0, stream>>>(x, ln1_g + l * 1024, ln1_b + l * 1024, h, 0);
        gemm_bt<<<dim3(24, 64), blk, 0, stream>>>(h, Wqkv_t + (long)l * 3145728, bqkv + l * 3072,
                                                  qkv, 8192, 3072, 1024, 3072, 0);
        flash_attn<<<dim3(16, 64), blk, 0, stream>>>(qkv, y);
        gemm_bt<<<dim3(8, 64), blk, 0, stream>>>(y, Wo_t + (long)l * 1048576, bo + l * 1024,
                                                 x, 8192, 1024, 1024, 1024, 2);
        ln_kernel<<<8192, blk, 0, stream>>>(x, ln2_g + l * 1024, ln2_b + l * 1024, h, 0);
        gemm_bt<<<dim3(16, 64), blk, 0, stream>>>(h, W1_t + (long)l * 2097152, b1 + l * 2048,
                                                  m1, 8192, 2048, 1024, 2048, 1);
        gemm_bt<<<dim3(8, 64), blk, 0, stream>>>(m1, W2_t + (long)l * 2097152, b2 + l * 1024,
                                                 x, 8192, 1024, 2048, 1024, 2);
    }

    ln_kernel<<<4096, blk, 0, stream>>>(x, lnf_g, lnf_b, hf, 1);
    gemm_bt<<<dim3(32, 32), blk, 0, stream>>>(hf, Wh_t, nullptr, d_out,
                                              4096, 4096, 1024, 4096, 3);
}